// Round 11
// baseline (3074.703 us; speedup 1.0000x reference)
//
#include <hip/hip_runtime.h>

typedef unsigned short u16;
typedef unsigned int   u32;
typedef __bf16 bf16x8 __attribute__((ext_vector_type(8)));
typedef float  f32x4  __attribute__((ext_vector_type(4)));
typedef u32    u32x2  __attribute__((ext_vector_type(2)));

#define DIMD  256
#define DIMH  512
#define NTHREADS 512

// Two 32-row tiles (A,B) per WG. LDS (u16 units), +16B row pads.
#define USTR 264
#define HSTR 520
#define UA_BASE 0
#define UB_BASE (32*USTR)                 // 8448
#define HA_BASE (2*32*USTR)               // 16896
#define HB_BASE (HA_BASE + 32*HSTR)       // 33536
#define LDS_U16 (HA_BASE + 2*32*HSTR)     // 50176 u16 = 100352 B (+32KB park)

#define DT 0.0625f

__device__ __forceinline__ u16 f2bf(float f) {          // RNE fp32->bf16
  u32 u = __float_as_uint(f);
  u += 0x7FFFu + ((u >> 16) & 1u);
  return (u16)(u >> 16);
}
__device__ __forceinline__ u32 pk(float a, float b) {
#if __has_builtin(__builtin_amdgcn_cvt_pk_bf16_f32)
  auto v = __builtin_amdgcn_cvt_pk_bf16_f32(a, b);      // v_cvt_pk_bf16_f32 (RNE)
  u32 r; __builtin_memcpy(&r, &v, 4); return r;
#else
  return (u32)f2bf(a) | ((u32)f2bf(b) << 16);
#endif
}
__device__ __forceinline__ float bflo(u32 p) { return __uint_as_float(p << 16); }
__device__ __forceinline__ float bfhi(u32 p) { return __uint_as_float(p & 0xFFFF0000u); }
__device__ __forceinline__ float tanh_fast(float x) {
  float e = __builtin_amdgcn_exp2f(x * 2.8853900817779268f);  // 2*log2(e)
  return 1.0f - 2.0f * __builtin_amdgcn_rcpf(e + 1.0f);
}

// LDS-only barrier: drain lgkmcnt, leave global weight prefetches in flight.
// 0xC07F = vmcnt(63) expcnt(7) lgkmcnt(0).
__device__ __forceinline__ void bar_lds() {
  asm volatile("" ::: "memory");
  __builtin_amdgcn_s_waitcnt(0xC07F);
  __builtin_amdgcn_s_barrier();
  asm volatile("" ::: "memory");
}

// W1[256][512] -> W1T bf16 [hcol=512][k=256]; W2[512][256] -> W2T bf16 [dcol=256][k=512]
__global__ void convert_w(const float* __restrict__ W1, const float* __restrict__ W2,
                          u16* __restrict__ w1t, u16* __restrict__ w2t) {
  int idx = blockIdx.x * 256 + threadIdx.x;
  {
    int n = idx >> 8, k = idx & 255;
    w1t[idx] = f2bf(W1[k * DIMH + n]);
  }
  {
    int n = idx >> 9, k = idx & 511;
    w2t[idx] = f2bf(W2[k * DIMD + n]);
  }
}

__device__ __forceinline__ void mfma_g1(f32x4 (&acc)[4][2],
                                        const bf16x8 (&a)[4], const bf16x8 (&b)[2]) {
#pragma unroll
  for (int mb = 0; mb < 4; ++mb)
#pragma unroll
    for (int nb = 0; nb < 2; ++nb)
      acc[mb][nb] = __builtin_amdgcn_mfma_f32_16x16x32_bf16(a[mb], b[nb], acc[mb][nb], 0, 0, 0);
}
__device__ __forceinline__ void mfma_g2(f32x4 (&acc)[2][2],
                                        const bf16x8 (&a)[2], const bf16x8 (&b)[2]) {
#pragma unroll
  for (int mb = 0; mb < 2; ++mb)
#pragma unroll
    for (int nb = 0; nb < 2; ++nb)
      acc[mb][nb] = __builtin_amdgcn_mfma_f32_16x16x32_bf16(a[mb], b[nb], acc[mb][nb], 0, 0, 0);
}

// Two-tile phase-interleaved schedule: each phase fuses G1(tile X) with
// G2(tile Y) in ONE K-loop, so G1's global loads are covered by G2's MFMAs
// of the INDEPENDENT tile (ILP, not TLP). The A/B split also makes u/h
// naturally double-buffered (phase writes h_Y,u_? disjoint from its reads).
// 1 WG/CU, 8 waves = 2 waves/EU = 256-reg budget (the only occupancy this
// state fits — rounds 4/7/8/9). Peak acc is 48 (vs round 6's 64).
__global__ __attribute__((amdgpu_flat_work_group_size(NTHREADS, NTHREADS),
                          amdgpu_waves_per_eu(2, 2)))
void ode_fused(
    const float* __restrict__ x,   const float* __restrict__ b1,
    const float* __restrict__ b2,  const float* __restrict__ wfc,
    const float* __restrict__ bfc, const u16* __restrict__ w1t,
    const u16* __restrict__ w2t,   float* __restrict__ out)
{
  __shared__ u16 lds[LDS_U16];
  __shared__ u32 k2f[16 * NTHREADS];     // k2 park, both tiles; [slot][tid]

  const int tid   = threadIdx.x;
  const int wg    = blockIdx.x;
  const int wv    = tid >> 6;          // wave 0..7
  const int lane  = tid & 63;
  const int lanel = lane & 15;
  const int laneq = lane >> 4;

  // Per-tile roles (32 rows each):
  //  G1: wave -> hcols wv*64 + mb*16 (mb 0..3), rows nb*16 (nb 0..1)
  //  G2: wave -> dcols wv*32 + mb*16 (mb 0..1), rows nb*16 (nb 0..1)
  //  Owned y: rows nb*16+lanel, dcols wv*32+mb*16+laneq*4+r
  //  flat i = nb*8 + mb*4 + r (16); pairs p = nb*4 + mb*2 + (r>>1) (8)

  u32 b1p[8], b2p[4];
#pragma unroll
  for (int mb = 0; mb < 4; ++mb) {
    int base = wv * 64 + mb * 16 + laneq * 4;
    b1p[mb * 2 + 0] = pk(b1[base + 0], b1[base + 1]);
    b1p[mb * 2 + 1] = pk(b1[base + 2], b1[base + 3]);
  }
#pragma unroll
  for (int mb = 0; mb < 2; ++mb) {
    int base = wv * 32 + mb * 16 + laneq * 4;
    b2p[mb * 2 + 0] = pk(b2[base + 0], b2[base + 1]);
    b2p[mb * 2 + 1] = pk(b2[base + 2], b2[base + 3]);
  }

  // Per-thread LDS pointers
  const u16* uRdA = &lds[UA_BASE + lanel * USTR + laneq * 8];
  const u16* uRdB = &lds[UB_BASE + lanel * USTR + laneq * 8];
  const u16* hRdA = &lds[HA_BASE + lanel * HSTR + laneq * 8];
  const u16* hRdB = &lds[HB_BASE + lanel * HSTR + laneq * 8];
  u16* uWrA = &lds[UA_BASE + lanel * USTR + wv * 32 + laneq * 4];
  u16* uWrB = &lds[UB_BASE + lanel * USTR + wv * 32 + laneq * 4];
  u16* hWrA = &lds[HA_BASE + lanel * HSTR + wv * 64 + laneq * 4];
  u16* hWrB = &lds[HB_BASE + lanel * HSTR + wv * 64 + laneq * 4];

  // fp32 y anchors + packed k-state per tile (st[0:8)=k1->u6d, st[8:16)=k3)
  float yvA[16], yvB[16];
  u32 stA[16], stB[16];

  // load x, write u1 for both tiles
#pragma unroll
  for (int nb = 0; nb < 2; ++nb)
#pragma unroll
    for (int mb = 0; mb < 2; ++mb) {
      int i = nb * 8 + mb * 4;
      {
        const float4 v = *(const float4*)&x[(wg * 64 + nb * 16 + lanel) * DIMD +
                                            wv * 32 + mb * 16 + laneq * 4];
        yvA[i] = v.x; yvA[i + 1] = v.y; yvA[i + 2] = v.z; yvA[i + 3] = v.w;
      }
      {
        const float4 v = *(const float4*)&x[(wg * 64 + 32 + nb * 16 + lanel) * DIMD +
                                            wv * 32 + mb * 16 + laneq * 4];
        yvB[i] = v.x; yvB[i + 1] = v.y; yvB[i + 2] = v.z; yvB[i + 3] = v.w;
      }
      u32x2 wA; wA.x = pk(yvA[i], yvA[i + 1]); wA.y = pk(yvA[i + 2], yvA[i + 3]);
      *(u32x2*)(uWrA + nb * 16 * USTR + mb * 16) = wA;
      u32x2 wB; wB.x = pk(yvB[i], yvB[i + 1]); wB.y = pk(yvB[i + 2], yvB[i + 3]);
      *(u32x2*)(uWrB + nb * 16 * USTR + mb * 16) = wB;
    }

  const u16* w1base[4];
#pragma unroll
  for (int mb = 0; mb < 4; ++mb)
    w1base[mb] = w1t + (wv * 64 + mb * 16 + lanel) * DIMD + laneq * 8;
  const u16* w2base[2];
#pragma unroll
  for (int mb = 0; mb < 2; ++mb)
    w2base[mb] = w2t + (wv * 32 + mb * 16 + lanel) * DIMH + laneq * 8;

  auto ldA1 = [&](bf16x8 (&a)[4], int kk) {
#pragma unroll
    for (int mb = 0; mb < 4; ++mb) a[mb] = *(const bf16x8*)(w1base[mb] + kk * 32);
  };
  auto ldB1 = [&](const u16* uRdX, bf16x8 (&b)[2], int kk) {
#pragma unroll
    for (int nb = 0; nb < 2; ++nb) b[nb] = *(const bf16x8*)(uRdX + nb * 16 * USTR + kk * 32);
  };
  auto ldA2 = [&](bf16x8 (&a)[2], int kk) {
#pragma unroll
    for (int mb = 0; mb < 2; ++mb) a[mb] = *(const bf16x8*)(w2base[mb] + kk * 32);
  };
  auto ldB2 = [&](const u16* hRdX, bf16x8 (&b)[2], int kk) {
#pragma unroll
    for (int nb = 0; nb < 2; ++nb) b[nb] = *(const bf16x8*)(hRdX + nb * 16 * HSTR + kk * 32);
  };

  bf16x8 aP1[4], aP2[2];   // next-phase kk=0 weight prefetch (cross-barrier)

  // ---- fused phase: G1(tile X via uRdX) + G2(tile Y via hRdY) ----
  auto fused_phase = [&](const u16* uRdX, const u16* hRdY,
                         f32x4 (&acc1)[4][2], f32x4 (&acc2)[2][2]) {
    bf16x8 a1c[4], b1c[2], a2c[2], b2c[2], a2n[2], b2n[2];
#pragma unroll
    for (int mb = 0; mb < 4; ++mb) a1c[mb] = aP1[mb];
#pragma unroll
    for (int mb = 0; mb < 2; ++mb) a2c[mb] = aP2[mb];
    ldB1(uRdX, b1c, 0);
    ldB2(hRdY, b2c, 0);
    ldA2(a2n, 1); ldB2(hRdY, b2n, 1);
#pragma unroll 1
    for (int j = 0; j < 7; ++j) {
      bf16x8 a1n[4], b1n[2], c2[2], d2[2], c3[2], d3[2];
      ldA1(a1n, j + 1); ldB1(uRdX, b1n, j + 1);
      mfma_g2(acc2, a2c, b2c);                       // G2 kk=2j
      ldA2(c2, 2 * j + 2); ldB2(hRdY, d2, 2 * j + 2);
      mfma_g2(acc2, a2n, b2n);                       // G2 kk=2j+1
      ldA2(c3, 2 * j + 3); ldB2(hRdY, d3, 2 * j + 3);
      mfma_g1(acc1, a1c, b1c);                       // G1 kk=j
#pragma unroll
      for (int mb = 0; mb < 4; ++mb) a1c[mb] = a1n[mb];
#pragma unroll
      for (int mb = 0; mb < 2; ++mb) {
        b1c[mb] = b1n[mb];
        a2c[mb] = c2[mb]; b2c[mb] = d2[mb];
        a2n[mb] = c3[mb]; b2n[mb] = d3[mb];
      }
    }
    // tail: G2 kk=14,15 ; G1 kk=7 ; next-phase weight prefetch
    mfma_g2(acc2, a2c, b2c);
    ldA1(aP1, 0);
    mfma_g2(acc2, a2n, b2n);
    ldA2(aP2, 0);
    mfma_g1(acc1, a1c, b1c);
  };

  auto ep1 = [&](u16* hWrX, f32x4 (&acc1)[4][2]) {
#pragma unroll
    for (int mb = 0; mb < 4; ++mb)
#pragma unroll
      for (int nb = 0; nb < 2; ++nb) {
        float h0 = tanh_fast(acc1[mb][nb][0] + bflo(b1p[mb * 2 + 0]));
        float h1 = tanh_fast(acc1[mb][nb][1] + bfhi(b1p[mb * 2 + 0]));
        float h2 = tanh_fast(acc1[mb][nb][2] + bflo(b1p[mb * 2 + 1]));
        float h3 = tanh_fast(acc1[mb][nb][3] + bfhi(b1p[mb * 2 + 1]));
        u32x2 w; w.x = pk(h0, h1); w.y = pk(h2, h3);
        *(u32x2*)(hWrX + nb * 16 * HSTR + mb * 16) = w;
      }
  };

  auto ep2 = [&](int s, float (&yv)[16], u32 (&st)[16], int pk2, u16* uWrX,
                 f32x4 (&acc2)[2][2]) {
    if (s == 1) {
      const float C = DT * 0.2f;
#pragma unroll
      for (int mb = 0; mb < 2; ++mb)
#pragma unroll
        for (int nb = 0; nb < 2; ++nb) {
          int i = nb * 8 + mb * 4, p = nb * 4 + mb * 2;
          float k0 = acc2[mb][nb][0] + bflo(b2p[mb * 2 + 0]);
          float k1 = acc2[mb][nb][1] + bfhi(b2p[mb * 2 + 0]);
          float k2 = acc2[mb][nb][2] + bflo(b2p[mb * 2 + 1]);
          float k3 = acc2[mb][nb][3] + bfhi(b2p[mb * 2 + 1]);
          st[p] = pk(k0, k1); st[p + 1] = pk(k2, k3);
          u32x2 w;
          w.x = pk(yv[i] + C * k0, yv[i + 1] + C * k1);
          w.y = pk(yv[i + 2] + C * k2, yv[i + 3] + C * k3);
          *(u32x2*)(uWrX + nb * 16 * USTR + mb * 16) = w;
        }
    } else if (s == 2) {
      const float C1 = DT * 0.075f, C2 = DT * 0.225f;
#pragma unroll
      for (int mb = 0; mb < 2; ++mb)
#pragma unroll
        for (int nb = 0; nb < 2; ++nb) {
          int i = nb * 8 + mb * 4, p = nb * 4 + mb * 2;
          float k0 = acc2[mb][nb][0] + bflo(b2p[mb * 2 + 0]);
          float k1 = acc2[mb][nb][1] + bfhi(b2p[mb * 2 + 0]);
          float k2 = acc2[mb][nb][2] + bflo(b2p[mb * 2 + 1]);
          float k3 = acc2[mb][nb][3] + bfhi(b2p[mb * 2 + 1]);
          k2f[(pk2 + p) * NTHREADS + tid]     = pk(k0, k1);
          k2f[(pk2 + p + 1) * NTHREADS + tid] = pk(k2, k3);
          u32x2 w;
          w.x = pk(yv[i]     + C1 * bflo(st[p])     + C2 * k0,
                   yv[i + 1] + C1 * bfhi(st[p])     + C2 * k1);
          w.y = pk(yv[i + 2] + C1 * bflo(st[p + 1]) + C2 * k2,
                   yv[i + 3] + C1 * bfhi(st[p + 1]) + C2 * k3);
          *(u32x2*)(uWrX + nb * 16 * USTR + mb * 16) = w;
        }
    } else if (s == 3) {
      const float C1 = DT * (float)(44.0/45.0);
      const float C2 = DT * (float)(-56.0/15.0);
      const float C3 = DT * (float)(32.0/9.0);
#pragma unroll
      for (int mb = 0; mb < 2; ++mb)
#pragma unroll
        for (int nb = 0; nb < 2; ++nb) {
          int i = nb * 8 + mb * 4, p = nb * 4 + mb * 2;
          float k0 = acc2[mb][nb][0] + bflo(b2p[mb * 2 + 0]);
          float k1 = acc2[mb][nb][1] + bfhi(b2p[mb * 2 + 0]);
          float k2 = acc2[mb][nb][2] + bflo(b2p[mb * 2 + 1]);
          float k3 = acc2[mb][nb][3] + bfhi(b2p[mb * 2 + 1]);
          st[8 + p] = pk(k0, k1); st[8 + p + 1] = pk(k2, k3);
          u32 q0 = k2f[(pk2 + p) * NTHREADS + tid];
          u32 q1 = k2f[(pk2 + p + 1) * NTHREADS + tid];
          u32x2 w;
          w.x = pk(yv[i]     + C1 * bflo(st[p])     + C2 * bflo(q0) + C3 * k0,
                   yv[i + 1] + C1 * bfhi(st[p])     + C2 * bfhi(q0) + C3 * k1);
          w.y = pk(yv[i + 2] + C1 * bflo(st[p + 1]) + C2 * bflo(q1) + C3 * k2,
                   yv[i + 3] + C1 * bfhi(st[p + 1]) + C2 * bfhi(q1) + C3 * k3);
          *(u32x2*)(uWrX + nb * 16 * USTR + mb * 16) = w;
        }
    } else if (s == 4) {
      const float C51 = DT * (float)(19372.0/6561.0);
      const float C52 = DT * (float)(-25360.0/2187.0);
      const float C53 = DT * (float)(64448.0/6561.0);
      const float C54 = DT * (float)(-212.0/729.0);
      const float D61 = DT * (float)(9017.0/3168.0  - 35.0/384.0);
      const float D62 = DT * (float)(-355.0/33.0);
      const float D63 = DT * (float)(46732.0/5247.0 - 500.0/1113.0);
      const float D64 = DT * (float)(49.0/176.0     - 125.0/192.0);
      const float E1  = DT * (float)(35.0/384.0);
      const float E3  = DT * (float)(500.0/1113.0);
      const float E4  = DT * (float)(125.0/192.0);
#pragma unroll
      for (int mb = 0; mb < 2; ++mb)
#pragma unroll
        for (int nb = 0; nb < 2; ++nb) {
          int i = nb * 8 + mb * 4, p = nb * 4 + mb * 2;
          float k40 = acc2[mb][nb][0] + bflo(b2p[mb * 2 + 0]);
          float k41 = acc2[mb][nb][1] + bfhi(b2p[mb * 2 + 0]);
          float k42 = acc2[mb][nb][2] + bflo(b2p[mb * 2 + 1]);
          float k43 = acc2[mb][nb][3] + bfhi(b2p[mb * 2 + 1]);
          float k10 = bflo(st[p]),     k11 = bfhi(st[p]);
          float k12 = bflo(st[p + 1]), k13 = bfhi(st[p + 1]);
          u32 q0 = k2f[(pk2 + p) * NTHREADS + tid];
          u32 q1 = k2f[(pk2 + p + 1) * NTHREADS + tid];
          float k20 = bflo(q0), k21 = bfhi(q0);
          float k22 = bflo(q1), k23 = bfhi(q1);
          float k30 = bflo(st[8 + p]),     k31 = bfhi(st[8 + p]);
          float k32 = bflo(st[8 + p + 1]), k33 = bfhi(st[8 + p + 1]);
          u32x2 w;
          w.x = pk(yv[i]     + C51 * k10 + C52 * k20 + C53 * k30 + C54 * k40,
                   yv[i + 1] + C51 * k11 + C52 * k21 + C53 * k31 + C54 * k41);
          w.y = pk(yv[i + 2] + C51 * k12 + C52 * k22 + C53 * k32 + C54 * k42,
                   yv[i + 3] + C51 * k13 + C52 * k23 + C53 * k33 + C54 * k43);
          *(u32x2*)(uWrX + nb * 16 * USTR + mb * 16) = w;
          st[p]     = pk(D61 * k10 + D62 * k20 + D63 * k30 + D64 * k40,
                         D61 * k11 + D62 * k21 + D63 * k31 + D64 * k41);
          st[p + 1] = pk(D61 * k12 + D62 * k22 + D63 * k32 + D64 * k42,
                         D61 * k13 + D62 * k23 + D63 * k33 + D64 * k43);
          yv[i]     += E1 * k10 + E3 * k30 + E4 * k40;
          yv[i + 1] += E1 * k11 + E3 * k31 + E4 * k41;
          yv[i + 2] += E1 * k12 + E3 * k32 + E4 * k42;
          yv[i + 3] += E1 * k13 + E3 * k33 + E4 * k43;
        }
    } else if (s == 5) {
      const float D65 = DT * (float)(-5103.0/18656.0 + 2187.0/6784.0);
      const float E5  = DT * (float)(-2187.0/6784.0);
#pragma unroll
      for (int mb = 0; mb < 2; ++mb)
#pragma unroll
        for (int nb = 0; nb < 2; ++nb) {
          int i = nb * 8 + mb * 4, p = nb * 4 + mb * 2;
          float k0 = acc2[mb][nb][0] + bflo(b2p[mb * 2 + 0]);
          float k1 = acc2[mb][nb][1] + bfhi(b2p[mb * 2 + 0]);
          float k2 = acc2[mb][nb][2] + bflo(b2p[mb * 2 + 1]);
          float k3 = acc2[mb][nb][3] + bfhi(b2p[mb * 2 + 1]);
          u32x2 w;
          w.x = pk(yv[i]     + bflo(st[p])     + D65 * k0,
                   yv[i + 1] + bfhi(st[p])     + D65 * k1);
          w.y = pk(yv[i + 2] + bflo(st[p + 1]) + D65 * k2,
                   yv[i + 3] + bfhi(st[p + 1]) + D65 * k3);
          *(u32x2*)(uWrX + nb * 16 * USTR + mb * 16) = w;
          yv[i]     += E5 * k0;
          yv[i + 1] += E5 * k1;
          yv[i + 2] += E5 * k2;
          yv[i + 3] += E5 * k3;
        }
    } else {
      const float E6 = DT * (float)(11.0/84.0);
#pragma unroll
      for (int mb = 0; mb < 2; ++mb)
#pragma unroll
        for (int nb = 0; nb < 2; ++nb) {
          int i = nb * 8 + mb * 4;
          yv[i]     += E6 * (acc2[mb][nb][0] + bflo(b2p[mb * 2 + 0]));
          yv[i + 1] += E6 * (acc2[mb][nb][1] + bfhi(b2p[mb * 2 + 0]));
          yv[i + 2] += E6 * (acc2[mb][nb][2] + bflo(b2p[mb * 2 + 1]));
          yv[i + 3] += E6 * (acc2[mb][nb][3] + bfhi(b2p[mb * 2 + 1]));
          u32x2 w;
          w.x = pk(yv[i], yv[i + 1]); w.y = pk(yv[i + 2], yv[i + 3]);
          *(u32x2*)(uWrX + nb * 16 * USTR + mb * 16) = w;
        }
    }
  };

  ldA1(aP1, 0);
  bar_lds();               // u1(A,B) visible; prefetch in flight

  // ---- warmup phase: G1_A(stage 0) only ----
  {
    f32x4 acc1[4][2];
#pragma unroll
    for (int mb = 0; mb < 4; ++mb)
#pragma unroll
      for (int nb = 0; nb < 2; ++nb) acc1[mb][nb] = (f32x4){0.f, 0.f, 0.f, 0.f};
    bf16x8 bb[2];
    ldB1(uRdA, bb, 0);
    mfma_g1(acc1, aP1, bb);
#pragma unroll 1
    for (int kk = 1; kk < 8; ++kk) {
      bf16x8 aa[4];
      ldA1(aa, kk); ldB1(uRdA, bb, kk);
      mfma_g1(acc1, aa, bb);
    }
    ldA1(aP1, 0);          // phase alpha(0) G1_B prefetch
    ldA2(aP2, 0);          // phase alpha(0) G2_A prefetch
    ep1(hWrA, acc1);
    bar_lds();
  }

  // ---- main loop: t = stage-slot (step*6 + s-1) ----
#pragma unroll 1
  for (int t = 0; t < 96; ++t) {
    int s = t - 6 * (t / 6) + 1;   // 1..6

    // phase alpha: G2_A(s) + G1_B
    {
      f32x4 acc1[4][2], acc2[2][2];
#pragma unroll
      for (int mb = 0; mb < 4; ++mb)
#pragma unroll
        for (int nb = 0; nb < 2; ++nb) acc1[mb][nb] = (f32x4){0.f, 0.f, 0.f, 0.f};
#pragma unroll
      for (int mb = 0; mb < 2; ++mb)
#pragma unroll
        for (int nb = 0; nb < 2; ++nb) acc2[mb][nb] = (f32x4){0.f, 0.f, 0.f, 0.f};
      fused_phase(uRdB, hRdA, acc1, acc2);
      ep2(s, yvA, stA, 0, uWrA, acc2);
      ep1(hWrB, acc1);
      bar_lds();
    }

    // phase beta: G1_A(next) + G2_B(s)   (at t=95 G1_A is harmless dummy work)
    {
      f32x4 acc1[4][2], acc2[2][2];
#pragma unroll
      for (int mb = 0; mb < 4; ++mb)
#pragma unroll
        for (int nb = 0; nb < 2; ++nb) acc1[mb][nb] = (f32x4){0.f, 0.f, 0.f, 0.f};
#pragma unroll
      for (int mb = 0; mb < 2; ++mb)
#pragma unroll
        for (int nb = 0; nb < 2; ++nb) acc2[mb][nb] = (f32x4){0.f, 0.f, 0.f, 0.f};
      fused_phase(uRdA, hRdB, acc1, acc2);
      ep1(hWrA, acc1);
      ep2(s, yvB, stB, 8, uWrB, acc2);
      bar_lds();
    }
  }

  // ---- out = y . Wfc + bfc (both tiles) ----
  {
    float wfcv[8];
#pragma unroll
    for (int mb = 0; mb < 2; ++mb)
#pragma unroll
      for (int r = 0; r < 4; ++r)
        wfcv[mb * 4 + r] = wfc[wv * 32 + mb * 16 + laneq * 4 + r];
    float* redf = (float*)lds;   // safe: last bar_lds drained all readers
    float prA[2], prB[2];
#pragma unroll
    for (int nb = 0; nb < 2; ++nb) {
      float pA = 0.f, pB = 0.f;
#pragma unroll
      for (int mb = 0; mb < 2; ++mb)
#pragma unroll
        for (int r = 0; r < 4; ++r) {
          pA += yvA[nb * 8 + mb * 4 + r] * wfcv[mb * 4 + r];
          pB += yvB[nb * 8 + mb * 4 + r] * wfcv[mb * 4 + r];
        }
      pA += __shfl_xor(pA, 16); pA += __shfl_xor(pA, 32);
      pB += __shfl_xor(pB, 16); pB += __shfl_xor(pB, 32);
      prA[nb] = pA; prB[nb] = pB;
    }
    if (laneq == 0) {
#pragma unroll
      for (int nb = 0; nb < 2; ++nb) {
        redf[(nb * 16 + lanel) * 8 + wv]        = prA[nb];
        redf[(32 + nb * 16 + lanel) * 8 + wv]   = prB[nb];
      }
    }
    __syncthreads();
    if (tid < 64) {
      float sm = bfc[0];
#pragma unroll
      for (int w = 0; w < 8; ++w) sm += redf[tid * 8 + w];
      out[wg * 64 + tid] = sm;
    }
  }
}

extern "C" void kernel_launch(void* const* d_in, const int* in_sizes, int n_in,
                              void* d_out, int out_size, void* d_ws, size_t ws_size,
                              hipStream_t stream) {
  const float* x   = (const float*)d_in[0];
  const float* W1  = (const float*)d_in[1];
  const float* b1  = (const float*)d_in[2];
  const float* W2  = (const float*)d_in[3];
  const float* b2  = (const float*)d_in[4];
  const float* wfc = (const float*)d_in[5];
  const float* bfc = (const float*)d_in[6];
  float* out = (float*)d_out;

  u16* w1t = (u16*)d_ws;                 // [512][256] bf16
  u16* w2t = w1t + DIMH * DIMD;          // [256][512] bf16

  hipLaunchKernelGGL(convert_w, dim3(512), dim3(256), 0, stream, W1, W2, w1t, w2t);
  hipLaunchKernelGGL(ode_fused, dim3(16384 / 64), dim3(NTHREADS), 0, stream,
                     x, b1, b2, wfc, bfc, w1t, w2t, out);
}